// Round 4
// baseline (948.320 us; speedup 1.0000x reference)
//
#include <hip/hip_runtime.h>

// fp8 blockwise-quantized GEMM for MI355X (gfx950) — round 7
//   y = (fp8(x/sx)*sx) @ (fp8(w)*sw)^T
// Round-6 post-mortem: counted-vmcnt top wait changed nothing (168 us,
// MfmaUtil 35%). Cycle accounting: 6300 cyc/kb-step vs MFMA pipe demand
// ~2500/SIMD and LDS pipe demand ~3000/CU -> the monolithic
// {reads -> lgkm0 -> MFMAs} phase serializes the LDS and matrix pipes at CU
// level (all 8 waves aligned by one barrier pair). We sit exactly at the
// known m97-structure MX-fp8 ceiling (1634 TF vs m148's 1628).
// Round-7: port the 8-phase template's per-phase interleave (the proven
// lever: 2-phase 607-682 -> 8-phase 1563-1728 TF bf16 at 256^2):
//   per kb-step, 4 phases of 8 MFMAs (f-half x g-half quadrant), each:
//   {issue 2 stage DMAs | issue phase ds_reads -> s_barrier -> lgkmcnt(0)
//    + sched_barrier -> setprio(1) 8 MFMA setprio(0) + rescale -> s_barrier}
//   Stage spread 2 DMAs/phase; ONE counted vmcnt(2) per kb-step at phase 0
//   (uniform: wave0's scale DMA issues LAST in phase 3, so prev-batch is
//   9 for wave0 / 8 for others and both resolve to vmcnt(2) with 2 newly
//   issued). No vmcnt(0) drain in the main loop.
// All constructs (raw barrier+fence, counted vmcnt, wave0-only scale DMA,
// readlane ws) were hardware-validated in round 6.

typedef int   v4i __attribute__((ext_vector_type(4)));
typedef int   v8i __attribute__((ext_vector_type(8)));
typedef float v4f __attribute__((ext_vector_type(4)));

constexpr int M  = 8192;
constexpr int K  = 4096;
constexpr int N  = 4096;
constexpr int KB = K / 128;  // 32
constexpr int NB = N / 128;  // 32

constexpr int XBLOCKS = (M * KB * 8) / 256;                    // 8192
constexpr int WBLOCKS = (int)(((long long)N * K / 16) / 256);  // 4096

#define GLOBAL_AS __attribute__((address_space(1)))
#define LDS_AS    __attribute__((address_space(3)))

__device__ __forceinline__ void async16(const void* g, void* l) {
  // 16B/lane global->LDS DMA; LDS dest = wave-uniform base (+ lane*16 by HW)
  __builtin_amdgcn_global_load_lds((const GLOBAL_AS void*)g, (LDS_AS void*)l, 16, 0, 0);
}

// Fragment-order layout for quantized Q[R][K]:
//   group (rf = r>>4, kb = k>>7) at base (rf*KB + kb)*2048
//   lane l = (k-quad)*16 + (r&15); lo16 @ base + l*16, hi16 @ base + 1024 + l*16
// matches the 16x16x128 f8f6f4 A/B operand layout (HW-validated rounds 1-6).

// ---------------- fused activation + weight quant ------------------------
__global__ __launch_bounds__(256) void quant_fused_kernel(
    const float* __restrict__ x, const float* __restrict__ w,
    unsigned char* __restrict__ xq, unsigned char* __restrict__ wq,
    float* __restrict__ xs_t /* [KB][M] */) {
  const int tid = threadIdx.x;
  if (blockIdx.x < XBLOCKS) {
    // ---- activation blockwise quant (fragment-order output) ----
    const long long blk = ((long long)blockIdx.x * 256 + tid) >> 3;  // over M*KB
    const int s = tid & 7;
    const int m  = (int)(blk >> 5);        // KB = 32
    const int kb = (int)(blk & (KB - 1));

    const float4* px = (const float4*)(x + blk * 128 + s * 16);
    float4 v0 = px[0], v1 = px[1], v2 = px[2], v3 = px[3];

    float ax = 0.f;
#define AMAX4(v) ax = fmaxf(ax, fmaxf(fmaxf(fabsf(v.x), fabsf(v.y)), fmaxf(fabsf(v.z), fabsf(v.w))))
    AMAX4(v0); AMAX4(v1); AMAX4(v2); AMAX4(v3);
#undef AMAX4
#pragma unroll
    for (int d = 4; d >= 1; d >>= 1) ax = fmaxf(ax, __shfl_xor(ax, d, 8));
    const float scale = fmaxf(ax, 1e-12f) / 448.0f;  // matches reference RNE path

    int p0 = 0, p1 = 0, p2 = 0, p3 = 0;
    p0 = __builtin_amdgcn_cvt_pk_fp8_f32(v0.x / scale, v0.y / scale, p0, false);
    p0 = __builtin_amdgcn_cvt_pk_fp8_f32(v0.z / scale, v0.w / scale, p0, true);
    p1 = __builtin_amdgcn_cvt_pk_fp8_f32(v1.x / scale, v1.y / scale, p1, false);
    p1 = __builtin_amdgcn_cvt_pk_fp8_f32(v1.z / scale, v1.w / scale, p1, true);
    p2 = __builtin_amdgcn_cvt_pk_fp8_f32(v2.x / scale, v2.y / scale, p2, false);
    p2 = __builtin_amdgcn_cvt_pk_fp8_f32(v2.z / scale, v2.w / scale, p2, true);
    p3 = __builtin_amdgcn_cvt_pk_fp8_f32(v3.x / scale, v3.y / scale, p3, false);
    p3 = __builtin_amdgcn_cvt_pk_fp8_f32(v3.z / scale, v3.w / scale, p3, true);

    const int q = s >> 1, j = s & 1, rr = m & 15;
    const long long base = ((long long)(m >> 4) * KB + kb) * 2048;
    *(v4i*)(xq + base + j * 1024 + (q * 16 + rr) * 16) = (v4i){p0, p1, p2, p3};

    if (s == 0) xs_t[(long long)kb * M + m] = scale;
  } else {
    // ---- weight fp8 cast (fragment-order output) ----
    const long long t = (long long)(blockIdx.x - XBLOCKS) * 256 + tid;  // N*K/16
    const int grp = (int)(t >> 7);
    const int idx = (int)(t & 127);
    const int l = idx >> 1, j = idx & 1;
    const int nf = grp >> 5, kb = grp & (KB - 1);
    const int n = nf * 16 + (l & 15);
    const int k = kb * 128 + (l >> 4) * 32 + j * 16;

    const float4* pw = (const float4*)(w + (long long)n * K + k);
    float4 v0 = pw[0], v1 = pw[1], v2 = pw[2], v3 = pw[3];
    int p0 = 0, p1 = 0, p2 = 0, p3 = 0;
    p0 = __builtin_amdgcn_cvt_pk_fp8_f32(v0.x, v0.y, p0, false);
    p0 = __builtin_amdgcn_cvt_pk_fp8_f32(v0.z, v0.w, p0, true);
    p1 = __builtin_amdgcn_cvt_pk_fp8_f32(v1.x, v1.y, p1, false);
    p1 = __builtin_amdgcn_cvt_pk_fp8_f32(v1.z, v1.w, p1, true);
    p2 = __builtin_amdgcn_cvt_pk_fp8_f32(v2.x, v2.y, p2, false);
    p2 = __builtin_amdgcn_cvt_pk_fp8_f32(v2.z, v2.w, p2, true);
    p3 = __builtin_amdgcn_cvt_pk_fp8_f32(v3.x, v3.y, p3, false);
    p3 = __builtin_amdgcn_cvt_pk_fp8_f32(v3.z, v3.w, p3, true);
    *(v4i*)(wq + (long long)grp * 2048 + j * 1024 + l * 16) = (v4i){p0, p1, p2, p3};
  }
}

// ---------------- 4-phase double-buffered fp8 GEMM, 256x256 tile ----------
// grid (N/256, M/256), 512 threads = 8 waves (wm 0..1 x wn 0..3); wave tile
// 128x64 = Fa8 x Fb4 fragments. Phases per kb-step (quadrants fh x gh):
//   P0: (f0-3, g0-1)  reads: B g01, A f0-3, sxr f0-3   stage: A pair0
//   P1: (f0-3, g2-3)  reads: B g23                     stage: A pair1
//   P2: (f4-7, g2-3)  reads: A f4-7, sxr f4-7          stage: B pair0
//   P3: (f4-7, g0-1)  reads: B g01 (re-read)           stage: B pair1 (+scale w0)
__global__ __launch_bounds__(512, 2) void gemm_fp8_kernel(
    const unsigned char* __restrict__ xq, const unsigned char* __restrict__ wq,
    const float* __restrict__ xs_t /*[KB][M]*/,
    const float* __restrict__ wscale /*[NB][KB]*/,
    float* __restrict__ out) {
  __shared__ unsigned char Asm[2][16 * 2048];  // 64 KB
  __shared__ unsigned char Bsm[2][16 * 2048];  // 64 KB
  __shared__ float Ssm[2][256];                // 2 KB

  const int tid   = threadIdx.x;
  const int ntile = blockIdx.x;  // 0..15
  const int mtile = blockIdx.y;  // 0..31
  const int wave  = tid >> 6;    // 0..7
  const int lane  = tid & 63;
  const int wm = wave >> 2, wn = wave & 3;
  const int l15 = lane & 15, quad = lane >> 4;

  // wave-uniform w-scale per kb, broadcast via readlane (validated r6)
  const float wsv = wscale[(ntile * 2 + (wn >> 1)) * KB + (lane & 31)];

  const unsigned char* pa0 =
      xq + ((long long)(mtile * 16 + wave * 2) * KB) * 2048 + lane * 16;
  const unsigned char* pb0 =
      wq + ((long long)(ntile * 16 + wave * 2) * KB) * 2048 + lane * 16;
  const char* ps0 = (const char*)(xs_t + (long long)mtile * 256) + lane * 16;

// stage one frag-group pair (2 x 1KB DMAs); pair = 0/1 selects the group
#define STAGE_A(nbuf, kbi, pair)                                               \
  {                                                                            \
    const long long koff_ = (long long)(kbi)*2048;                             \
    async16(pa0 + koff_ + (long long)(pair) * (KB * 2048),                     \
            &Asm[nbuf][(wave * 2 + (pair)) * 2048]);                           \
    async16(pa0 + koff_ + (long long)(pair) * (KB * 2048) + 1024,              \
            &Asm[nbuf][(wave * 2 + (pair)) * 2048 + 1024]);                    \
  }
#define STAGE_B(nbuf, kbi, pair)                                               \
  {                                                                            \
    const long long koff_ = (long long)(kbi)*2048;                             \
    async16(pb0 + koff_ + (long long)(pair) * (KB * 2048),                     \
            &Bsm[nbuf][(wave * 2 + (pair)) * 2048]);                           \
    async16(pb0 + koff_ + (long long)(pair) * (KB * 2048) + 1024,              \
            &Bsm[nbuf][(wave * 2 + (pair)) * 2048 + 1024]);                    \
  }
#define STAGE_S(nbuf, kbi)                                                     \
  async16(ps0 + (long long)(kbi) * (M * 4), &Ssm[nbuf][0])

#define LDBF(g, dst)                                                           \
  {                                                                            \
    const unsigned char* pb_ = Bq + (wn * 4 + (g)) * 2048 + lane * 16;         \
    v4i lo_ = *(const v4i*)pb_;                                                \
    v4i hi_ = *(const v4i*)(pb_ + 1024);                                       \
    dst[0] = lo_[0]; dst[1] = lo_[1]; dst[2] = lo_[2]; dst[3] = lo_[3];        \
    dst[4] = hi_[0]; dst[5] = hi_[1]; dst[6] = hi_[2]; dst[7] = hi_[3];        \
  }
#define LDAF(f, dst)                                                           \
  {                                                                            \
    const unsigned char* pa_ = Aq + (wm * 8 + (f)) * 2048 + lane * 16;         \
    v4i lo_ = *(const v4i*)pa_;                                                \
    v4i hi_ = *(const v4i*)(pa_ + 1024);                                       \
    dst[0] = lo_[0]; dst[1] = lo_[1]; dst[2] = lo_[2]; dst[3] = lo_[3];        \
    dst[4] = hi_[0]; dst[5] = hi_[1]; dst[6] = hi_[2]; dst[7] = hi_[3];        \
  }

#define FENCE asm volatile("" ::: "memory")
#define LGKM0_PIN                                                              \
  asm volatile("s_waitcnt lgkmcnt(0)" ::: "memory");                           \
  __builtin_amdgcn_sched_barrier(0)

// 8-MFMA quadrant + exact f32 rescale. a4/sx4 hold f-half FH*4..+3; b2 holds
// g-half G0,G0+1. All indices compile-time (unrolled) -> stays in registers.
#define CLUSTER(FH, G0)                                                        \
  {                                                                            \
    __builtin_amdgcn_s_setprio(1);                                             \
    _Pragma("unroll") for (int fl = 0; fl < 4; ++fl) {                         \
      v4f p0_ = __builtin_amdgcn_mfma_scale_f32_16x16x128_f8f6f4(              \
          a4[fl], b2[0], zf, 0, 0, 0, 0x7f7f7f7f, 0, 0x7f7f7f7f);              \
      v4f p1_ = __builtin_amdgcn_mfma_scale_f32_16x16x128_f8f6f4(              \
          a4[fl], b2[1], zf, 0, 0, 0, 0x7f7f7f7f, 0, 0x7f7f7f7f);              \
      acc[(FH)*4 + fl][(G0)] += sx4[fl] * p0_;                                 \
      acc[(FH)*4 + fl][(G0) + 1] += sx4[fl] * p1_;                             \
    }                                                                          \
    __builtin_amdgcn_s_setprio(0);                                             \
  }

  v4f acc[8][4];
#pragma unroll
  for (int f = 0; f < 8; ++f)
#pragma unroll
    for (int g = 0; g < 4; ++g) acc[f][g] = (v4f){0.f, 0.f, 0.f, 0.f};
  const v4f zf = (v4f){0.f, 0.f, 0.f, 0.f};

  // prologue: full batch for kb=0 (A0,A1,B0,B1,scale-last: 8 loads, w0 9)
  STAGE_A(0, 0, 0); STAGE_A(0, 0, 1);
  STAGE_B(0, 0, 0); STAGE_B(0, 0, 1);
  if (wave == 0) STAGE_S(0, 0);

  v8i a4[4], b2[2];
  v4f sx4[4];

#pragma unroll 1
  for (int kb = 0; kb < KB; ++kb) {
    const int cur = kb & 1, nxt = cur ^ 1;
    const bool pref = (kb < KB - 1);
    const unsigned char* Aq = Asm[cur];
    const unsigned char* Bq = Bsm[cur];
    const float ws =
        __uint_as_float(__builtin_amdgcn_readlane(__float_as_uint(wsv), kb));

    // ---- P0: quadrant (f0-3, g0-1) ----
    if (pref) STAGE_A(nxt, kb + 1, 0);
    if (pref) asm volatile("s_waitcnt vmcnt(2)" ::: "memory");  // prev batch done
    else      asm volatile("s_waitcnt vmcnt(0)" ::: "memory");
    __builtin_amdgcn_s_barrier();  // cur buffer valid across all waves
    FENCE; __builtin_amdgcn_sched_barrier(0);
    LDBF(0, b2[0]); LDBF(1, b2[1]);
#pragma unroll
    for (int fl = 0; fl < 4; ++fl) LDAF(fl, a4[fl]);
#pragma unroll
    for (int fl = 0; fl < 4; ++fl)
      sx4[fl] = *(const v4f*)&Ssm[cur][wm * 128 + fl * 16 + quad * 4];
    LGKM0_PIN;
#pragma unroll
    for (int fl = 0; fl < 4; ++fl) sx4[fl] *= ws;
    CLUSTER(0, 0);
    FENCE; __builtin_amdgcn_s_barrier();

    // ---- P1: quadrant (f0-3, g2-3) ----
    if (pref) STAGE_A(nxt, kb + 1, 1);
    LDBF(2, b2[0]); LDBF(3, b2[1]);
    FENCE; __builtin_amdgcn_s_barrier();
    LGKM0_PIN;
    CLUSTER(0, 2);
    FENCE; __builtin_amdgcn_s_barrier();

    // ---- P2: quadrant (f4-7, g2-3)  (b2 still holds g2,g3) ----
    if (pref) STAGE_B(nxt, kb + 1, 0);
#pragma unroll
    for (int fl = 0; fl < 4; ++fl) LDAF(4 + fl, a4[fl]);
#pragma unroll
    for (int fl = 0; fl < 4; ++fl)
      sx4[fl] = *(const v4f*)&Ssm[cur][wm * 128 + (4 + fl) * 16 + quad * 4];
    FENCE; __builtin_amdgcn_s_barrier();
    LGKM0_PIN;
#pragma unroll
    for (int fl = 0; fl < 4; ++fl) sx4[fl] *= ws;
    CLUSTER(1, 2);
    FENCE; __builtin_amdgcn_s_barrier();

    // ---- P3: quadrant (f4-7, g0-1) ----
    if (pref) STAGE_B(nxt, kb + 1, 1);
    if (pref && wave == 0) STAGE_S(nxt, kb + 1);  // scale LAST in batch
    LDBF(0, b2[0]); LDBF(1, b2[1]);  // re-read g0,g1
    FENCE; __builtin_amdgcn_s_barrier();
    LGKM0_PIN;
    CLUSTER(1, 0);
    FENCE; __builtin_amdgcn_s_barrier();
  }

  // ---- epilogue: C/D layout col = lane&15, row = quad*4 + reg ----
#pragma unroll
  for (int f = 0; f < 8; ++f) {
#pragma unroll
    for (int r = 0; r < 4; ++r) {
      const long long row = mtile * 256 + wm * 128 + f * 16 + quad * 4 + r;
      float* po = out + row * N + ntile * 256 + wn * 64 + l15;
#pragma unroll
      for (int g = 0; g < 4; ++g) po[g * 16] = acc[f][g][r];
    }
  }
}

extern "C" void kernel_launch(void* const* d_in, const int* in_sizes, int n_in,
                              void* d_out, int out_size, void* d_ws, size_t ws_size,
                              hipStream_t stream) {
  const float* x   = (const float*)d_in[0];  // [M,K]
  const float* w   = (const float*)d_in[1];  // [N,K]
  const float* wsc = (const float*)d_in[2];  // [NB,KB]
  float* out = (float*)d_out;                // [M,N] f32

  unsigned char* ws = (unsigned char*)d_ws;
  unsigned char* xq = ws;                                      // 32 MB frag-order
  unsigned char* wq = ws + (size_t)M * K;                      // 16 MB frag-order
  float* xs_t = (float*)(ws + (size_t)M * K + (size_t)N * K);  // 1 MB [KB][M]

  quant_fused_kernel<<<XBLOCKS + WBLOCKS, 256, 0, stream>>>(x, w, xq, wq, xs_t);
  gemm_fp8_kernel<<<dim3(N / 256, M / 256), 512, 0, stream>>>(xq, wq, xs_t, wsc, out);
}

// Round 5
// 403.372 us; speedup vs baseline: 2.3510x; 2.3510x over previous
//
#include <hip/hip_runtime.h>

// fp8 blockwise-quantized GEMM for MI355X (gfx950) — round 8
//   y = (fp8(x/sx)*sx) @ (fp8(w)*sw)^T
// Round-7 post-mortem: 4-phase GEMM spilled the accumulator (WRITE_SIZE
// 1.6 GB scratch traffic, MfmaUtil 8%) -> reverted to the round-6 GEMM
// verbatim (168 us, VGPR 104, zero scratch).
// Round-8 change (single, isolated): x-quant thread mapping. Old mapping
// gave each wave 1 m-row x 8 kb -> 64x16B writes scattered as 8x128B pieces
// across 8 fragment groups; a group needed stores from 16 different
// workgroups to fill a line. New mapping: workgroup = 16 rows x 2 kb = 2
// COMPLETE 2KB fragment groups; a wave writes 8 dense 128B runs in one
// group (full 64B lines). Reads stay coalesced (512B row chunks); the
// 8-lane shfl reduce and exact-division rounding are unchanged. w-quant
// and GEMM byte-identical to round 6.
// Non-GEMM time is ~255us in rounds 0 AND 3 (total - gemm), > the GEMM
// itself, while quant's memory roofline is ~38us -> quant is the target.

typedef int   v4i __attribute__((ext_vector_type(4)));
typedef int   v8i __attribute__((ext_vector_type(8)));
typedef float v4f __attribute__((ext_vector_type(4)));

constexpr int M  = 8192;
constexpr int K  = 4096;
constexpr int N  = 4096;
constexpr int KB = K / 128;  // 32
constexpr int NB = N / 128;  // 32

constexpr int XBLOCKS = (M / 16) * (KB / 2);                   // 8192: 2 groups/wg
constexpr int WBLOCKS = (int)(((long long)N * K / 16) / 256);  // 4096

#define GLOBAL_AS __attribute__((address_space(1)))
#define LDS_AS    __attribute__((address_space(3)))

__device__ __forceinline__ void async16(const void* g, void* l) {
  // 16B/lane global->LDS DMA; LDS dest = wave-uniform base (+ lane*16 by HW)
  __builtin_amdgcn_global_load_lds((const GLOBAL_AS void*)g, (LDS_AS void*)l, 16, 0, 0);
}

// Fragment-order layout for quantized Q[R][K]:
//   group (rf = r>>4, kb = k>>7) at base (rf*KB + kb)*2048
//   k-chunk s (16 elems), row rr: byte (s&1)*1024 + ((s>>1)*16 + rr)*16
// matches the 16x16x128 f8f6f4 A/B operand layout (HW-validated rounds 1-6).

// ---------------- fused activation + weight quant ------------------------
__global__ __launch_bounds__(256) void quant_fused_kernel(
    const float* __restrict__ x, const float* __restrict__ w,
    unsigned char* __restrict__ xq, unsigned char* __restrict__ wq,
    float* __restrict__ xs_t /* [KB][M] */) {
  const int tid = threadIdx.x;
  if (blockIdx.x < XBLOCKS) {
    // ---- activation blockwise quant: wg = 16 rows x 2 kb (2 groups) ----
    const int gid2 = blockIdx.x;
    const int mf  = gid2 >> 4;        // 0..511 (row-block)
    const int kbp = gid2 & 15;        // 0..15  (kb pair)
    const int kb2 = tid >> 7;         // 0..1
    const int rr  = (tid >> 3) & 15;  // row within block
    const int s   = tid & 7;          // 16-elem k-chunk
    const int kb  = kbp * 2 + kb2;
    const int m   = mf * 16 + rr;

    const float4* px = (const float4*)(x + (long long)m * K + kb * 128 + s * 16);
    float4 v0 = px[0], v1 = px[1], v2 = px[2], v3 = px[3];

    float ax = 0.f;
#define AMAX4(v) ax = fmaxf(ax, fmaxf(fmaxf(fabsf(v.x), fabsf(v.y)), fmaxf(fabsf(v.z), fabsf(v.w))))
    AMAX4(v0); AMAX4(v1); AMAX4(v2); AMAX4(v3);
#undef AMAX4
#pragma unroll
    for (int d = 4; d >= 1; d >>= 1) ax = fmaxf(ax, __shfl_xor(ax, d, 8));
    const float scale = fmaxf(ax, 1e-12f) / 448.0f;  // matches reference RNE path

    int p0 = 0, p1 = 0, p2 = 0, p3 = 0;
    p0 = __builtin_amdgcn_cvt_pk_fp8_f32(v0.x / scale, v0.y / scale, p0, false);
    p0 = __builtin_amdgcn_cvt_pk_fp8_f32(v0.z / scale, v0.w / scale, p0, true);
    p1 = __builtin_amdgcn_cvt_pk_fp8_f32(v1.x / scale, v1.y / scale, p1, false);
    p1 = __builtin_amdgcn_cvt_pk_fp8_f32(v1.z / scale, v1.w / scale, p1, true);
    p2 = __builtin_amdgcn_cvt_pk_fp8_f32(v2.x / scale, v2.y / scale, p2, false);
    p2 = __builtin_amdgcn_cvt_pk_fp8_f32(v2.z / scale, v2.w / scale, p2, true);
    p3 = __builtin_amdgcn_cvt_pk_fp8_f32(v3.x / scale, v3.y / scale, p3, false);
    p3 = __builtin_amdgcn_cvt_pk_fp8_f32(v3.z / scale, v3.w / scale, p3, true);

    const int q = s >> 1, j = s & 1;
    *(v4i*)(xq + ((long long)(mf * KB + kb)) * 2048 + j * 1024 +
            (q * 16 + rr) * 16) = (v4i){p0, p1, p2, p3};

    if (s == 0) xs_t[(long long)kb * M + m] = scale;
  } else {
    // ---- weight fp8 cast (fragment-order output) — unchanged ----
    const long long t = (long long)(blockIdx.x - XBLOCKS) * 256 + tid;  // N*K/16
    const int grp = (int)(t >> 7);
    const int idx = (int)(t & 127);
    const int l = idx >> 1, j = idx & 1;
    const int nf = grp >> 5, kb = grp & (KB - 1);
    const int n = nf * 16 + (l & 15);
    const int k = kb * 128 + (l >> 4) * 32 + j * 16;

    const float4* pw = (const float4*)(w + (long long)n * K + k);
    float4 v0 = pw[0], v1 = pw[1], v2 = pw[2], v3 = pw[3];
    int p0 = 0, p1 = 0, p2 = 0, p3 = 0;
    p0 = __builtin_amdgcn_cvt_pk_fp8_f32(v0.x, v0.y, p0, false);
    p0 = __builtin_amdgcn_cvt_pk_fp8_f32(v0.z, v0.w, p0, true);
    p1 = __builtin_amdgcn_cvt_pk_fp8_f32(v1.x, v1.y, p1, false);
    p1 = __builtin_amdgcn_cvt_pk_fp8_f32(v1.z, v1.w, p1, true);
    p2 = __builtin_amdgcn_cvt_pk_fp8_f32(v2.x, v2.y, p2, false);
    p2 = __builtin_amdgcn_cvt_pk_fp8_f32(v2.z, v2.w, p2, true);
    p3 = __builtin_amdgcn_cvt_pk_fp8_f32(v3.x, v3.y, p3, false);
    p3 = __builtin_amdgcn_cvt_pk_fp8_f32(v3.z, v3.w, p3, true);
    *(v4i*)(wq + (long long)grp * 2048 + j * 1024 + l * 16) = (v4i){p0, p1, p2, p3};
  }
}

// ---------------- double-buffered fp8 GEMM, 256x256 block tile ----------
// (byte-identical to round 6: 168 us, MfmaUtil 35%, zero scratch)
// grid (N/256, M/256), 512 threads = 8 waves (wm 0..1 x wn 0..3); wave tile
// 128x64 = Fa8 x Fb4 fragments. Per kb-step each wave stages 8 x 1KB tile
// DMAs (wave 0: +1 scale-row DMA) into the *next* buffer, waits a COUNTED
// vmcnt for its own previous batch, raw-barriers, computes; bottom sync is
// __syncthreads() (tail-only drain: the batch was issued before compute).
__global__ __launch_bounds__(512, 2) void gemm_fp8_kernel(
    const unsigned char* __restrict__ xq, const unsigned char* __restrict__ wq,
    const float* __restrict__ xs_t /*[KB][M]*/,
    const float* __restrict__ wscale /*[NB][KB]*/,
    float* __restrict__ out) {
  __shared__ unsigned char Asm[2][16 * 2048];  // 64 KB: 16 A frag-groups x2
  __shared__ unsigned char Bsm[2][16 * 2048];  // 64 KB: 16 B frag-groups x2
  __shared__ float Ssm[2][256];                // 2 KB: x-scale row x2

  const int tid   = threadIdx.x;
  const int ntile = blockIdx.x;  // 0..15 (256-col tiles)
  const int mtile = blockIdx.y;  // 0..31 (256-row tiles)
  const int wave  = tid >> 6;    // 0..7
  const int lane  = tid & 63;
  const int wm = wave >> 2, wn = wave & 3;
  const int l15 = lane & 15, quad = lane >> 4;

  // per-wave w-scale: wave's 64 cols sit inside ONE 128-col scale block, so
  // ws is wave-uniform; readlane(wsv, kb) broadcasts it each iteration.
  const float wsv = wscale[(ntile * 2 + (wn >> 1)) * KB + (lane & 31)];

  const unsigned char* pa0 =
      xq + ((long long)(mtile * 16 + wave * 2) * KB) * 2048 + lane * 16;
  const unsigned char* pb0 =
      wq + ((long long)(ntile * 16 + wave * 2) * KB) * 2048 + lane * 16;
  const char* ps0 = (const char*)(xs_t + (long long)mtile * 256) + lane * 16;

  auto STAGE = [&](int nbuf, int kbi) {
    const long long koff = (long long)kbi * 2048;
#pragma unroll
    for (int t = 0; t < 4; ++t)  // A: group wave*2 + (t>>1), half t&1
      async16(pa0 + koff + (long long)(t >> 1) * (KB * 2048) + (t & 1) * 1024,
              &Asm[nbuf][(wave * 2 + (t >> 1)) * 2048 + (t & 1) * 1024]);
#pragma unroll
    for (int t = 0; t < 4; ++t)  // B: group wave*2 + (t>>1), half t&1
      async16(pb0 + koff + (long long)(t >> 1) * (KB * 2048) + (t & 1) * 1024,
              &Bsm[nbuf][(wave * 2 + (t >> 1)) * 2048 + (t & 1) * 1024]);
    // x-scale row (1KB): staged by wave 0 only (vmcnt is per-wave).
    if (wave == 0) async16(ps0 + (long long)kbi * (M * 4), &Ssm[nbuf][0]);
  };

  v4f acc[8][4];
#pragma unroll
  for (int f = 0; f < 8; ++f)
#pragma unroll
    for (int g = 0; g < 4; ++g) acc[f][g] = (v4f){0.f, 0.f, 0.f, 0.f};

  const v4f z = (v4f){0.f, 0.f, 0.f, 0.f};

  STAGE(0, 0);  // prologue prefetch

#pragma unroll 1
  for (int kb = 0; kb < KB; ++kb) {
    const int cur = kb & 1;
    if (kb < KB - 1) {
      STAGE(cur ^ 1, kb + 1);  // next-buffer batch; stays in flight over compute
      // wait only for THIS WAVE's previous batch (FIFO-oldest):
      if (wave == 0) asm volatile("s_waitcnt vmcnt(9)" ::: "memory");
      else           asm volatile("s_waitcnt vmcnt(8)" ::: "memory");
    } else {
      asm volatile("s_waitcnt vmcnt(0)" ::: "memory");
    }
    __builtin_amdgcn_s_barrier();  // everyone's cur-buffer DMAs retired
    // s_barrier is not an IR memory fence: pin cross-wave-dependent LDS reads
    // below it (compiler fence + scheduler fence).
    asm volatile("" ::: "memory");
    __builtin_amdgcn_sched_barrier(0);

    const float ws =
        __uint_as_float(__builtin_amdgcn_readlane(__float_as_uint(wsv), kb));

    // ---- B fragments (shared across all f) ----
    v8i b[4];
#pragma unroll
    for (int g = 0; g < 4; ++g) {
      const unsigned char* pb = Bsm[cur] + (wn * 4 + g) * 2048 + lane * 16;
      v4i lo = *(const v4i*)pb;
      v4i hi = *(const v4i*)(pb + 1024);
      b[g][0] = lo[0]; b[g][1] = lo[1]; b[g][2] = lo[2]; b[g][3] = lo[3];
      b[g][4] = hi[0]; b[g][5] = hi[1]; b[g][6] = hi[2]; b[g][7] = hi[3];
    }

    // ---- per A-fragment: load, 4 MFMA, exact f32 rescale ----
#pragma unroll
    for (int f = 0; f < 8; ++f) {
      const unsigned char* pa = Asm[cur] + (wm * 8 + f) * 2048 + lane * 16;
      v4i lo = *(const v4i*)pa;
      v4i hi = *(const v4i*)(pa + 1024);
      v8i a;
      a[0] = lo[0]; a[1] = lo[1]; a[2] = lo[2]; a[3] = lo[3];
      a[4] = hi[0]; a[5] = hi[1]; a[6] = hi[2]; a[7] = hi[3];
      const v4f sxr = *(const v4f*)&Ssm[cur][wm * 128 + f * 16 + quad * 4];
      const v4f s = sxr * ws;
      v4f p[4];
      __builtin_amdgcn_s_setprio(1);
#pragma unroll
      for (int g = 0; g < 4; ++g) {
        // unit e8m0 scales (0x7F = 2^0): plain fp8 K=128 dot at MX rate
        p[g] = __builtin_amdgcn_mfma_scale_f32_16x16x128_f8f6f4(
            a, b[g], z, 0, 0, 0, 0x7f7f7f7f, 0, 0x7f7f7f7f);
      }
      __builtin_amdgcn_s_setprio(0);
#pragma unroll
      for (int g = 0; g < 4; ++g) acc[f][g] += s * p[g];
    }
    // bottom sync: drains this iteration's prefetch batch (tail-only: it had
    // the whole compute phase to land) and protects cur from next-iter DMA.
    __syncthreads();
  }

  // ---- epilogue: C/D layout col = lane&15, row = quad*4 + reg ----
#pragma unroll
  for (int f = 0; f < 8; ++f) {
#pragma unroll
    for (int r = 0; r < 4; ++r) {
      const long long row = mtile * 256 + wm * 128 + f * 16 + quad * 4 + r;
      float* po = out + row * N + ntile * 256 + wn * 64 + l15;
#pragma unroll
      for (int g = 0; g < 4; ++g) po[g * 16] = acc[f][g][r];
    }
  }
}

extern "C" void kernel_launch(void* const* d_in, const int* in_sizes, int n_in,
                              void* d_out, int out_size, void* d_ws, size_t ws_size,
                              hipStream_t stream) {
  const float* x   = (const float*)d_in[0];  // [M,K]
  const float* w   = (const float*)d_in[1];  // [N,K]
  const float* wsc = (const float*)d_in[2];  // [NB,KB]
  float* out = (float*)d_out;                // [M,N] f32

  unsigned char* ws = (unsigned char*)d_ws;
  unsigned char* xq = ws;                                      // 32 MB frag-order
  unsigned char* wq = ws + (size_t)M * K;                      // 16 MB frag-order
  float* xs_t = (float*)(ws + (size_t)M * K + (size_t)N * K);  // 1 MB [KB][M]

  quant_fused_kernel<<<XBLOCKS + WBLOCKS, 256, 0, stream>>>(x, w, xq, wq, xs_t);
  gemm_fp8_kernel<<<dim3(N / 256, M / 256), 512, 0, stream>>>(xq, wq, xs_t, wsc, out);
}